// Round 4
// baseline (250.730 us; speedup 1.0000x reference)
//
#include <hip/hip_runtime.h>
#include <math.h>

#define BB 32
#define SS 2048
#define EE 128
#define NH 8
#define HDIM 16
#define CACHE_LEN 256
#define SINKS 4
#define WINDOW 128
#define KSEL (SINKS + WINDOW)   // 132
#define ROWS (BB * SS)          // 65536

typedef int v4i __attribute__((ext_vector_type(4)));

// workspace layout (bytes)
#define WS_MAXX 0                         // int bits of max|x| (nonneg float as int)
#define WS_MAXO 4                         // int bits of max|attn_out|
#define WS_WS   16                        // float[4] w_scales (q,k,v,o)
#define WS_W(i) (256 + (i) * 16384)       // ternary int8, row-major [o][e]
#define WS_QBUF (256 + 4 * 16384)         // q rows, head-major: [b][h][s][16] f32

// d_out layout: [0, ROWS*128) attn-out then final output (in-place o_proj);
// new_k at ROWS*128, new_v at ROWS*128 + 524288
#define NKV_N (BB * NH * WINDOW * HDIM)   // 524288

// ---- fused weight prep (blocks 0..3) + max|x| (blocks 4..515) -----------
__global__ void prep_and_max(const float* __restrict__ qw, const float* __restrict__ kw,
                             const float* __restrict__ vw, const float* __restrict__ ow,
                             const float* __restrict__ x, char* __restrict__ ws) {
    const int tid = threadIdx.x;
    if (blockIdx.x < 4) {
        const float* W[4] = {qw, kw, vw, ow};
        const int m = blockIdx.x;
        const float* w = W[m];
        __shared__ double red[256];
        double s = 0.0;
        for (int j = tid; j < 16384; j += 256) s += fabs((double)w[j]);
        red[tid] = s;
        __syncthreads();
        for (int st = 128; st > 0; st >>= 1) {
            if (tid < st) red[tid] += red[tid + st];
            __syncthreads();
        }
        const double wscale = red[0] / 16384.0;
        const double thr = 0.5 * wscale;
        if (tid == 0) ((float*)(ws + WS_WS))[m] = (float)wscale;
        signed char* tw = (signed char*)(ws + WS_W(m));
        for (int j = tid; j < 16384; j += 256) {
            const float wv = w[j];
            const double av = fabs((double)wv);
            tw[j] = (av > thr) ? (wv > 0.f ? (signed char)1 : (signed char)-1) : (signed char)0;
        }
    } else {
        __shared__ float red[256];
        float mx = 0.f;
        const int n4 = ROWS * EE / 4;
        const int nthreads = 512 * 256;
        for (int i = (blockIdx.x - 4) * 256 + tid; i < n4; i += nthreads) {
            const float4 v = ((const float4*)x)[i];
            mx = fmaxf(mx, fmaxf(fmaxf(fabsf(v.x), fabsf(v.y)), fmaxf(fabsf(v.z), fabsf(v.w))));
        }
        red[tid] = mx;
        __syncthreads();
        for (int st = 128; st > 0; st >>= 1) {
            if (tid < st) red[tid] = fmaxf(red[tid], red[tid + st]);
            __syncthreads();
        }
        // nonneg float bits as signed int: int-max == float-max; poison (0xAA..) is negative
        if (tid == 0) atomicMax((int*)(ws + WS_MAXX), __float_as_int(red[0]));
    }
}

// ---- int8 MFMA QKV projection -------------------------------------------
// blocks 0..1023: Q (all rows) -> QBUF head-major
// blocks 1024..1151: K,V (window rows only) -> new_k/new_v region of d_out
__global__ __launch_bounds__(256) void qkv_proj_mfma(const float* __restrict__ x,
                                                     const float* __restrict__ qb,
                                                     const float* __restrict__ kb,
                                                     const float* __restrict__ vb,
                                                     char* __restrict__ ws,
                                                     float* __restrict__ out) {
    const int bx = blockIdx.x;
    const int tid = threadIdx.x;
    int proj, in_row0, b_blk, s0;   // s0: seq offset (Q) or window offset (K/V)
    if (bx < 1024) {
        proj = 0; in_row0 = bx * 64; b_blk = bx >> 5; s0 = (bx * 64) & 2047;
    } else {
        int widx = bx - 1024;
        proj = 1 + (widx >> 6);
        widx &= 63;
        b_blk = widx >> 1;
        s0 = (widx & 1) * 64;
        in_row0 = b_blk * 2048 + (SS - WINDOW) + s0;
    }
    const float* bias = (proj == 0) ? qb : (proj == 1) ? kb : vb;
    const signed char* tw = (const signed char*)(ws + WS_W(proj));
    float* dst = (proj == 0) ? (float*)(ws + WS_QBUF)
               : (proj == 1) ? (out + (size_t)ROWS * EE)
                             : (out + (size_t)ROWS * EE + NKV_N);

    const int lane = tid & 63;
    const int wv = tid >> 6;
    const int ml = lane & 15;
    const int quad = lane >> 4;

    v4i bfrag[8][2];
#pragma unroll
    for (int c = 0; c < 8; ++c)
#pragma unroll
        for (int s = 0; s < 2; ++s)
            bfrag[c][s] = *(const v4i*)(tw + (c * 16 + ml) * 128 + s * 64 + quad * 16);

    __shared__ __align__(16) signed char lds_a[64 * 144];
    const float maxx = __int_as_float(*(const int*)(ws + WS_MAXX));
    const float iscale = maxx / 127.0f;
    const float4* x4 = (const float4*)(x + (size_t)in_row0 * 128);
#pragma unroll
    for (int it = 0; it < 8; ++it) {
        const int i = tid + it * 256;
        const int row = i >> 5, c4 = i & 31;
        const float4 v = x4[i];
        float a0 = fminf(fmaxf(rintf(v.x / iscale), -128.f), 127.f);
        float a1 = fminf(fmaxf(rintf(v.y / iscale), -128.f), 127.f);
        float a2 = fminf(fmaxf(rintf(v.z / iscale), -128.f), 127.f);
        float a3 = fminf(fmaxf(rintf(v.w / iscale), -128.f), 127.f);
        const int i0 = (int)a0, i1 = (int)a1, i2 = (int)a2, i3 = (int)a3;
        const int packed = (i0 & 0xff) | ((i1 & 0xff) << 8) | ((i2 & 0xff) << 16) | (i3 << 24);
        *(int*)(lds_a + row * 144 + c4 * 4) = packed;
    }
    __syncthreads();

    const v4i afrag0 = *(const v4i*)(lds_a + (wv * 16 + ml) * 144 + quad * 16);
    const v4i afrag1 = *(const v4i*)(lds_a + (wv * 16 + ml) * 144 + 64 + quad * 16);

    const float wsc = ((const float*)(ws + WS_WS))[proj];
    const float scale = wsc * iscale;

#pragma unroll
    for (int c = 0; c < 8; ++c) {
        v4i acc = {0, 0, 0, 0};
        acc = __builtin_amdgcn_mfma_i32_16x16x64_i8(afrag0, bfrag[c][0], acc, 0, 0, 0);
        acc = __builtin_amdgcn_mfma_i32_16x16x64_i8(afrag1, bfrag[c][1], acc, 0, 0, 0);
        const int col = c * 16 + ml;
        const int h = col >> 4, d = col & 15;
        const float bcol = bias[col];
        const int slen = (proj == 0) ? SS : WINDOW;
#pragma unroll
        for (int r = 0; r < 4; ++r) {
            const int srow = s0 + wv * 16 + quad * 4 + r;
            dst[((size_t)(b_blk * NH + h) * slen + srow) * 16 + d] = (float)acc[r] * scale + bcol;
        }
    }
}

// ---- attention: 1 query/thread; K/V rows read with wave-uniform addrs ----
// j is a loop counter (uniform) -> compiler emits scalar (SMEM) loads of the
// K/V rows; v_fmac uses them as the one-SGPR operand. No LDS in inner loop.
__global__ __launch_bounds__(256, 8) void attention(const float* __restrict__ ck,
                                                    const float* __restrict__ cv,
                                                    char* __restrict__ ws,
                                                    float* __restrict__ out) {
    const int qt = blockIdx.x, h = blockIdx.y, b = blockIdx.z;
    const int tid = threadIdx.x;
    const int qi = qt * 256 + tid;
    const int hb = b * NH + h;
    __shared__ float red[256];

    const float* ckh = ck + (size_t)hb * CACHE_LEN * 16;
    const float* cvh = cv + (size_t)hb * CACHE_LEN * 16;
    const float* nk = out + (size_t)ROWS * EE + (size_t)hb * WINDOW * 16;
    const float* nv = nk + NKV_N;
    const float* qrow = (const float*)(ws + WS_QBUF) + ((size_t)hb * SS + qi) * 16;

    float q[16];
#pragma unroll
    for (int i = 0; i < 4; ++i) {
        const float4 v = ((const float4*)qrow)[i];
        q[i * 4 + 0] = v.x * 0.25f;   // fold 1/sqrt(16) (exact pow2)
        q[i * 4 + 1] = v.y * 0.25f;
        q[i * 4 + 2] = v.z * 0.25f;
        q[i * 4 + 3] = v.w * 0.25f;
    }
    const int jmax = (qi < KSEL - 1) ? qi : (KSEL - 1);
    float m, l = 0.f;
    float o[16];
#pragma unroll
    for (int d = 0; d < 16; ++d) o[d] = 0.f;

    // ---- sink chunk (4 keys) ----
    {
        float sc[4];
        float mc = -INFINITY;
#pragma unroll
        for (int i = 0; i < 4; ++i) {
            const float* kr = ckh + i * 16;
            float s = 0.f;
#pragma unroll
            for (int z = 0; z < 4; ++z) {
                const float4 kv = ((const float4*)kr)[z];
                s = fmaf(q[z * 4 + 0], kv.x, s);
                s = fmaf(q[z * 4 + 1], kv.y, s);
                s = fmaf(q[z * 4 + 2], kv.z, s);
                s = fmaf(q[z * 4 + 3], kv.w, s);
            }
            sc[i] = (i <= jmax) ? s : -INFINITY;
            mc = fmaxf(mc, sc[i]);
        }
        m = mc;   // o,l are zero; no rescale needed for first chunk
#pragma unroll
        for (int i = 0; i < 4; ++i) {
            const float p = __expf(sc[i] - m);
            l += p;
            const float* vr = cvh + i * 16;
#pragma unroll
            for (int z = 0; z < 4; ++z) {
                const float4 vv = ((const float4*)vr)[z];
                o[z * 4 + 0] = fmaf(p, vv.x, o[z * 4 + 0]);
                o[z * 4 + 1] = fmaf(p, vv.y, o[z * 4 + 1]);
                o[z * 4 + 2] = fmaf(p, vv.z, o[z * 4 + 2]);
                o[z * 4 + 3] = fmaf(p, vv.w, o[z * 4 + 3]);
            }
        }
    }

    // ---- window: 16 chunks x 8 keys ----
#pragma unroll 1
    for (int ch = 0; ch < 16; ++ch) {
        const float* kbase = nk + ch * 8 * 16;
        float sc[8];
        float mc = -INFINITY;
#pragma unroll
        for (int i = 0; i < 8; ++i) {
            const float* kr = kbase + i * 16;
            float s = 0.f;
#pragma unroll
            for (int z = 0; z < 4; ++z) {
                const float4 kv = ((const float4*)kr)[z];
                s = fmaf(q[z * 4 + 0], kv.x, s);
                s = fmaf(q[z * 4 + 1], kv.y, s);
                s = fmaf(q[z * 4 + 2], kv.z, s);
                s = fmaf(q[z * 4 + 3], kv.w, s);
            }
            const int j = SINKS + ch * 8 + i;
            sc[i] = (j <= jmax) ? s : -INFINITY;
            mc = fmaxf(mc, sc[i]);
        }
        const float mn = fmaxf(m, mc);
        const float cs = __expf(m - mn);
        l *= cs;
#pragma unroll
        for (int d = 0; d < 16; ++d) o[d] *= cs;
        m = mn;
        const float* vbase = nv + ch * 8 * 16;
#pragma unroll
        for (int i = 0; i < 8; ++i) {
            const float p = __expf(sc[i] - m);
            l += p;
            const float* vr = vbase + i * 16;
#pragma unroll
            for (int z = 0; z < 4; ++z) {
                const float4 vv = ((const float4*)vr)[z];
                o[z * 4 + 0] = fmaf(p, vv.x, o[z * 4 + 0]);
                o[z * 4 + 1] = fmaf(p, vv.y, o[z * 4 + 1]);
                o[z * 4 + 2] = fmaf(p, vv.z, o[z * 4 + 2]);
                o[z * 4 + 3] = fmaf(p, vv.w, o[z * 4 + 3]);
            }
        }
    }

    const float inv = 1.0f / l;
    float tm = 0.f;
    float* ao = out + (size_t)(b * SS + qi) * 128 + h * 16;
#pragma unroll
    for (int i = 0; i < 4; ++i) {
        float4 v;
        v.x = o[i * 4 + 0] * inv;
        v.y = o[i * 4 + 1] * inv;
        v.z = o[i * 4 + 2] * inv;
        v.w = o[i * 4 + 3] * inv;
        tm = fmaxf(tm, fmaxf(fmaxf(fabsf(v.x), fabsf(v.y)), fmaxf(fabsf(v.z), fabsf(v.w))));
        ((float4*)ao)[i] = v;
    }
    red[tid] = tm;
    __syncthreads();
    for (int st = 128; st > 0; st >>= 1) {
        if (tid < st) red[tid] = fmaxf(red[tid], red[tid + st]);
        __syncthreads();
    }
    if (tid == 0) atomicMax((int*)(ws + WS_MAXO), __float_as_int(red[0]));
}

// ---- O projection, int8 MFMA, in-place on d_out -------------------------
__global__ __launch_bounds__(256) void o_proj_mfma(const float* __restrict__ ob,
                                                   char* __restrict__ ws,
                                                   float* __restrict__ out) {
    const int bx = blockIdx.x;
    const int tid = threadIdx.x;
    const int in_row0 = bx * 64;
    const signed char* tw = (const signed char*)(ws + WS_W(3));

    const int lane = tid & 63;
    const int wv = tid >> 6;
    const int ml = lane & 15;
    const int quad = lane >> 4;

    v4i bfrag[8][2];
#pragma unroll
    for (int c = 0; c < 8; ++c)
#pragma unroll
        for (int s = 0; s < 2; ++s)
            bfrag[c][s] = *(const v4i*)(tw + (c * 16 + ml) * 128 + s * 64 + quad * 16);

    __shared__ __align__(16) signed char lds_a[64 * 144];
    const float maxo = __int_as_float(*(const int*)(ws + WS_MAXO));
    const float iscale = maxo / 127.0f;
    const float4* x4 = (const float4*)(out + (size_t)in_row0 * 128);
#pragma unroll
    for (int it = 0; it < 8; ++it) {
        const int i = tid + it * 256;
        const int row = i >> 5, c4 = i & 31;
        const float4 v = x4[i];
        float a0 = fminf(fmaxf(rintf(v.x / iscale), -128.f), 127.f);
        float a1 = fminf(fmaxf(rintf(v.y / iscale), -128.f), 127.f);
        float a2 = fminf(fmaxf(rintf(v.z / iscale), -128.f), 127.f);
        float a3 = fminf(fmaxf(rintf(v.w / iscale), -128.f), 127.f);
        const int i0 = (int)a0, i1 = (int)a1, i2 = (int)a2, i3 = (int)a3;
        const int packed = (i0 & 0xff) | ((i1 & 0xff) << 8) | ((i2 & 0xff) << 16) | (i3 << 24);
        *(int*)(lds_a + row * 144 + c4 * 4) = packed;
    }
    __syncthreads();

    const v4i afrag0 = *(const v4i*)(lds_a + (wv * 16 + ml) * 144 + quad * 16);
    const v4i afrag1 = *(const v4i*)(lds_a + (wv * 16 + ml) * 144 + 64 + quad * 16);

    const float wsc = ((const float*)(ws + WS_WS))[3];
    const float scale = wsc * iscale;

#pragma unroll
    for (int c = 0; c < 8; ++c) {
        v4i acc = {0, 0, 0, 0};
        acc = __builtin_amdgcn_mfma_i32_16x16x64_i8(afrag0, bfrag[c][0], acc, 0, 0, 0);
        acc = __builtin_amdgcn_mfma_i32_16x16x64_i8(afrag1, bfrag[c][1], acc, 0, 0, 0);
        const int col = c * 16 + ml;
        const float bcol = ob[col];
#pragma unroll
        for (int r = 0; r < 4; ++r) {
            const int row = wv * 16 + quad * 4 + r;
            out[(size_t)(in_row0 + row) * 128 + col] = (float)acc[r] * scale + bcol;
        }
    }
}

extern "C" void kernel_launch(void* const* d_in, const int* in_sizes, int n_in,
                              void* d_out, int out_size, void* d_ws, size_t ws_size,
                              hipStream_t stream) {
    const float* x  = (const float*)d_in[0];
    const float* ck = (const float*)d_in[1];
    const float* cv = (const float*)d_in[2];
    const float* qw = (const float*)d_in[3];
    const float* qb = (const float*)d_in[4];
    const float* kw = (const float*)d_in[5];
    const float* kb = (const float*)d_in[6];
    const float* vw = (const float*)d_in[7];
    const float* vb = (const float*)d_in[8];
    const float* ow = (const float*)d_in[9];
    const float* ob = (const float*)d_in[10];
    char* ws = (char*)d_ws;
    float* out = (float*)d_out;

    prep_and_max<<<4 + 512, 256, 0, stream>>>(qw, kw, vw, ow, x, ws);
    qkv_proj_mfma<<<1024 + 128, 256, 0, stream>>>(x, qb, kb, vb, ws, out);
    attention<<<dim3(8, NH, BB), 256, 0, stream>>>(ck, cv, ws, out);
    o_proj_mfma<<<1024, 256, 0, stream>>>(ob, ws, out);
}